// Round 3
// baseline (719.166 us; speedup 1.0000x reference)
//
#include <hip/hip_runtime.h>
#include <cstdint>
#include <cstddef>

#define Bb 4
#define Nn 384
#define Ff 128
#define Tt 8

typedef __attribute__((ext_vector_type(8))) __bf16 bf16x8;
typedef __attribute__((ext_vector_type(4))) float fv4;

// ---------- bf16 helpers (RNE) ----------
static __device__ __forceinline__ unsigned int pack2bf(float lo, float hi) {
    union { float f; unsigned int i; } ca, cb;
    ca.f = lo; cb.f = hi;
    unsigned int a = (ca.i + 0x7fffu + ((ca.i >> 16) & 1u)) >> 16;
    unsigned int b = (cb.i + 0x7fffu + ((cb.i >> 16) & 1u)) & 0xffff0000u;
    return a | b;
}
static __device__ __forceinline__ unsigned short f2bf(float f) {
    union { float f; unsigned int i; } c; c.f = f;
    return (unsigned short)((c.i + 0x7fffu + ((c.i >> 16) & 1u)) >> 16);
}

// ---------- K1: per-(b,n) precompute of broadcast terms + reduction-buffer init ----------
__global__ __launch_bounds__(128) void k_pre(
    const float* __restrict__ node, const float* __restrict__ hidden,
    const float* __restrict__ graph,
    const float* __restrict__ W_m1, const float* __restrict__ b_m1,
    const float* __restrict__ W_m2, const float* __restrict__ b_m2,
    const float* __restrict__ b_me,
    const float* __restrict__ W_mg, const float* __restrict__ b_mg,
    const float* __restrict__ W_tn1, const float* __restrict__ b_tn1,
    const float* __restrict__ W_tn2, const float* __restrict__ b_tn2,
    const float* __restrict__ W_th1, const float* __restrict__ b_th1,
    const float* __restrict__ W_th2, const float* __restrict__ b_th2,
    const float* __restrict__ W_tg1, const float* __restrict__ b_tg1,
    const float* __restrict__ W_tg2, const float* __restrict__ b_tg2,
    const float* __restrict__ b_te1, const float* __restrict__ b_te2,
    float* __restrict__ preA, float* __restrict__ preB,
    float* __restrict__ triA, float* __restrict__ triB,
    int* __restrict__ msgs_i, int* __restrict__ az)
{
    int bn = blockIdx.x;          // b*Nn + n
    int b  = bn / Nn;
    int t  = threadIdx.x;         // 0..127 == output channel m
    __shared__ float sn[Ff], sh[Ff], sg[Ff];
    sn[t] = node[(size_t)bn * Ff + t];
    sh[t] = hidden[(size_t)bn * Ff + t];
    sg[t] = graph[b * Ff + t];
    __syncthreads();

    float a = b_m1[t] + b_mg[t] + b_me[t];
    float h = b_m2[t];
    for (int k = 0; k < Ff; ++k) {
        a = fmaf(sn[k], W_m1[k * Ff + t], a);
        a = fmaf(sg[k], W_mg[k * Ff + t], a);
        h = fmaf(sh[k], W_m2[k * Ff + t], h);
    }
    preA[(size_t)bn * Ff + t] = a;
    preB[(size_t)bn * Ff + t] = h;
    msgs_i[(size_t)bn * Ff + t] = (int)0x80000000;   // INT_MIN: below any encoded key
    if (t == 0) az[bn] = 0;

    if (t < 2 * Tt) {
        int tt = t & 7;
        if (t < Tt) {
            float v = b_tn1[tt] + b_th1[tt] + b_tg1[tt] + b_tg2[tt] + b_te1[tt] + b_te2[tt];
            for (int k = 0; k < Ff; ++k)
                v += sn[k] * W_tn1[k * Tt + tt] + sh[k] * W_th1[k * Tt + tt]
                   + sg[k] * (W_tg1[k * Tt + tt] + W_tg2[k * Tt + tt]);
            triA[bn * Tt + tt] = v;
        } else {
            float v = b_tn2[tt] + b_th2[tt];
            for (int k = 0; k < Ff; ++k)
                v += sn[k] * W_tn2[k * Tt + tt] + sh[k] * W_th2[k * Tt + tt];
            triB[bn * Tt + tt] = v;
        }
    }
}

// ---------- K2: build W_T bf16 [144 rows][136 stride] ----------
// rows 0..127: W_me^T ; rows 128..135: (W_te1+W_te2)^T ; rows 136..143: zeros
__global__ __launch_bounds__(256) void k_prew(
    const float* __restrict__ W_me, const float* __restrict__ W_te1,
    const float* __restrict__ W_te2, unsigned short* __restrict__ wt)
{
    int idx = blockIdx.x * 256 + threadIdx.x;
    if (idx >= 144 * 136) return;
    int row = idx / 136, kc = idx % 136;
    float v = 0.f;
    if (kc < 128) {
        if (row < 128)      v = W_me[kc * Ff + row];
        else if (row < 136) v = W_te1[kc * Tt + (row - 128)] + W_te2[kc * Tt + (row - 128)];
    }
    wt[idx] = f2bf(v);
}

// ---------- K3: fused edge pass, barrier-free K-loop, A-frags direct from global ----------
// grid 768 = b(4) x jblk(12) x iblk(16); block tile = 24 i x 32 j; 12 chunks of 2 i.
#define EST 136
#define WT_ROWS 144
#define LDS_WT  (WT_ROWS * EST * 2)        // 39168 B (>= 32768 needed by S-reduce reuse)
#define LDS_TA  (32 * 8 * 4)               // 1024 B
#define LDS_ADJ (24 * 32 * 4)              // 3072 B

__global__ __launch_bounds__(256, 3) void k_main(
    const float* __restrict__ edge, const float* __restrict__ adj,
    const unsigned short* __restrict__ wt,
    const float* __restrict__ preB,
    const float* __restrict__ triA, const float* __restrict__ triB,
    int* __restrict__ msgs_i, int* __restrict__ az,
    float* __restrict__ tri_out)
{
    __shared__ char smem[LDS_WT + LDS_TA + LDS_ADJ];   // 43264 B -> 3 blocks/CU
    unsigned short* WT  = (unsigned short*)smem;
    float*          sTA = (float*)(smem + LDS_WT);
    float*          sADJ= (float*)(smem + LDS_WT + LDS_TA);

    int bx   = blockIdx.x;
    int iblk = bx & 15, jblk = (bx >> 4) % 12, b = bx / 192;
    int i0 = iblk * 24, j0 = jblk * 32;
    int t = threadIdx.x, lane = t & 63, w = t >> 6;
    int l15 = lane & 15, quad = lane >> 4;
    int ih = w >> 1, jh = w & 1;

    // one-time LDS staging
    for (int idx = t; idx < LDS_WT / 16; idx += 256)
        ((uint4*)WT)[idx] = ((const uint4*)wt)[idx];
    if (t < 256)
        sTA[t] = triA[(b * Nn + j0 + (t >> 3)) * Tt + (t & 7)];
    for (int idx = t; idx < 768; idx += 256)
        sADJ[idx] = adj[(size_t)(b * Nn + i0 + (idx >> 5)) * Nn + j0 + (idx & 31)];
    __syncthreads();

    float mx[8][4];
    #pragma unroll
    for (int nt = 0; nt < 8; ++nt)
        #pragma unroll
        for (int r = 0; r < 4; ++r) mx[nt][r] = -1e30f;

    // wave's A-row base: rows = 16 j's (j0+jh*16+l15), i = i0 + c*2 + ih
    const float* ebase = edge + ((size_t)(b * Nn + i0 + ih) * Nn + j0 + jh * 16 + l15) * Ff + quad * 8;

    float4 c0[4], c1[4];
    #pragma unroll
    for (int kk = 0; kk < 4; ++kk) {
        c0[kk] = *(const float4*)(ebase + kk * 32);
        c1[kk] = *(const float4*)(ebase + kk * 32 + 4);
    }

    for (int c = 0; c < 12; ++c) {
        int il  = c * 2 + ih;
        int i_g = i0 + il;

        // convert current chunk fp32 -> bf16 A-frags
        bf16x8 af[4];
        #pragma unroll
        for (int kk = 0; kk < 4; ++kk) {
            union { uint4 u; bf16x8 v; } cv;
            cv.u.x = pack2bf(c0[kk].x, c0[kk].y);
            cv.u.y = pack2bf(c0[kk].z, c0[kk].w);
            cv.u.z = pack2bf(c1[kk].x, c1[kk].y);
            cv.u.w = pack2bf(c1[kk].z, c1[kk].w);
            af[kk] = cv.v;
        }
        // prefetch next chunk
        if (c + 1 < 12) {
            const float* p = ebase + (size_t)(c + 1) * (2 * Nn * Ff);
            #pragma unroll
            for (int kk = 0; kk < 4; ++kk) {
                c0[kk] = *(const float4*)(p + kk * 32);
                c1[kk] = *(const float4*)(p + kk * 32 + 4);
            }
        }

        fv4 acc[8], at;
        #pragma unroll
        for (int nt = 0; nt < 8; ++nt) acc[nt] = (fv4){0.f, 0.f, 0.f, 0.f};
        at = (fv4){0.f, 0.f, 0.f, 0.f};

        #pragma unroll
        for (int kk = 0; kk < 4; ++kk) {
            int ko = kk * 32 + quad * 8;
            bf16x8 bt = *(const bf16x8*)&WT[(128 + l15) * EST + ko];
            at = __builtin_amdgcn_mfma_f32_16x16x32_bf16(af[kk], bt, at, 0, 0, 0);
            #pragma unroll
            for (int nt = 0; nt < 8; ++nt) {
                bf16x8 bq = *(const bf16x8*)&WT[(nt * 16 + l15) * EST + ko];
                acc[nt] = __builtin_amdgcn_mfma_f32_16x16x32_bf16(af[kk], bq, acc[nt], 0, 0, 0);
            }
        }

        // epilogue: online masked max (additive mask) + tri write
        const float* pbp = &preB[(size_t)(b * Nn + i_g) * Ff];
        float pbv[8];
        #pragma unroll
        for (int nt = 0; nt < 8; ++nt) pbv[nt] = pbp[nt * 16 + l15];
        float tbv = triB[(b * Nn + i_g) * Tt + (l15 & 7)];
        #pragma unroll
        for (int r = 0; r < 4; ++r) {
            int jl = jh * 16 + quad * 4 + r;
            float adjv = sADJ[il * 32 + jl];
            float mr = fmaf(adjv, 1e30f, -1e30f);      // adj=1 -> 0, adj=0 -> -1e30
            #pragma unroll
            for (int nt = 0; nt < 8; ++nt)
                mx[nt][r] = fmaxf(mx[nt][r], acc[nt][r] + pbv[nt] + mr);
            float tv = at[r] + sTA[jl * 8 + (l15 & 7)] + tbv;
            if (l15 < 8)
                tri_out[((size_t)(b * Nn + i_g) * Nn + j0 + jl) * Tt + l15] = fmaxf(tv, 0.f);
        }
    }

    // cross-wave max reduce (reuse WT area: 32 KB needed, 39168 available)
    __syncthreads();
    float* S = (float*)smem;
    #pragma unroll
    for (int r = 0; r < 4; ++r) {
        int jq = quad * 4 + r;
        #pragma unroll
        for (int nt = 0; nt < 8; ++nt)
            S[w * 2048 + jq * 128 + nt * 16 + l15] = mx[nt][r];
    }
    if (t < 32) {                      // anyzero flag per j (sADJ region untouched by S)
        int any0 = 0;
        for (int il2 = 0; il2 < 24; ++il2) any0 |= (sADJ[il2 * 32 + t] == 0.f);
        if (any0) atomicOr(&az[b * Nn + j0 + t], 1);
    }
    __syncthreads();
    #pragma unroll
    for (int e = 0; e < 16; ++e) {
        int idx = e * 256 + t;                 // jl*128 + m
        int jl = idx >> 7, m = idx & 127;
        int jh2 = jl >> 4, jq = jl & 15;
        float v = fmaxf(S[jh2 * 2048 + jq * 128 + m], S[(jh2 + 2) * 2048 + jq * 128 + m]);
        int iv  = __float_as_int(v);
        int key = iv >= 0 ? iv : (iv ^ 0x7fffffff);   // order-preserving int encoding
        atomicMax(&msgs_i[(size_t)(b * Nn + j0 + jl) * Ff + m], key);
    }
}

// ---------- K4: decode max, add preA, anyzero clamp, output head ----------
__global__ __launch_bounds__(128) void k_out(
    const float* __restrict__ node, const float* __restrict__ hidden,
    const int* __restrict__ msgs_i, const int* __restrict__ az,
    const float* __restrict__ preA,
    const float* __restrict__ W_o1, const float* __restrict__ b_o1,
    const float* __restrict__ W_o2, const float* __restrict__ b_o2,
    const float* __restrict__ W_o3, const float* __restrict__ b_o3,
    float* __restrict__ out)
{
    int bn = blockIdx.x;
    int t  = threadIdx.x;
    __shared__ float sn[Ff], sh[Ff], sm[Ff];
    sn[t] = node[(size_t)bn * Ff + t];
    sh[t] = hidden[(size_t)bn * Ff + t];
    int iv = msgs_i[(size_t)bn * Ff + t];
    int dk = iv >= 0 ? iv : (iv ^ 0x7fffffff);
    float mv = __int_as_float(dk) + preA[(size_t)bn * Ff + t];
    if (az[bn] != 0) mv = fmaxf(mv, 0.f);
    sm[t] = mv;
    __syncthreads();
    float v = b_o1[t] + b_o2[t] + b_o3[t];
    for (int k = 0; k < Ff; ++k) {
        v = fmaf(sn[k], W_o1[k * Ff + t], v);
        v = fmaf(sh[k], W_o2[k * Ff + t], v);
        v = fmaf(sm[k], W_o3[k * Ff + t], v);
    }
    out[(size_t)bn * Ff + t] = v;
}

extern "C" void kernel_launch(void* const* d_in, const int* in_sizes, int n_in,
                              void* d_out, int out_size, void* d_ws, size_t ws_size,
                              hipStream_t stream)
{
    const float* node   = (const float*)d_in[0];
    const float* edge   = (const float*)d_in[1];
    const float* graph  = (const float*)d_in[2];
    const float* adj    = (const float*)d_in[3];
    const float* hidden = (const float*)d_in[4];
    const float* W_m1 = (const float*)d_in[5];  const float* b_m1 = (const float*)d_in[6];
    const float* W_m2 = (const float*)d_in[7];  const float* b_m2 = (const float*)d_in[8];
    const float* W_me = (const float*)d_in[9];  const float* b_me = (const float*)d_in[10];
    const float* W_mg = (const float*)d_in[11]; const float* b_mg = (const float*)d_in[12];
    const float* W_o1 = (const float*)d_in[13]; const float* b_o1 = (const float*)d_in[14];
    const float* W_o2 = (const float*)d_in[15]; const float* b_o2 = (const float*)d_in[16];
    const float* W_o3 = (const float*)d_in[17]; const float* b_o3 = (const float*)d_in[18];
    const float* W_tn1 = (const float*)d_in[19]; const float* b_tn1 = (const float*)d_in[20];
    const float* W_tn2 = (const float*)d_in[21]; const float* b_tn2 = (const float*)d_in[22];
    const float* W_th1 = (const float*)d_in[23]; const float* b_th1 = (const float*)d_in[24];
    const float* W_th2 = (const float*)d_in[25]; const float* b_th2 = (const float*)d_in[26];
    const float* W_te1 = (const float*)d_in[27]; const float* b_te1 = (const float*)d_in[28];
    const float* W_te2 = (const float*)d_in[29]; const float* b_te2 = (const float*)d_in[30];
    const float* W_tg1 = (const float*)d_in[31]; const float* b_tg1 = (const float*)d_in[32];
    const float* W_tg2 = (const float*)d_in[33]; const float* b_tg2 = (const float*)d_in[34];

    float* ws   = (float*)d_ws;
    float* preA = ws;                               // 196608 f
    float* preB = preA + 196608;                    // 196608 f
    float* triA = preB + 196608;                    // 12288 f
    float* triB = triA + 12288;                     // 12288 f
    int*   msgs_i = (int*)(triB + 12288);           // 196608 i
    int*   az     = msgs_i + 196608;                // 1536 i
    unsigned short* wt = (unsigned short*)(az + 1536);  // 19584 us  (total ~2.5 MB)

    float* ret = (float*)d_out;                     // (4,384,128)
    float* tri = ret + (size_t)Bb * Nn * Ff;        // (4,384,384,8)

    hipLaunchKernelGGL(k_pre, dim3(Bb * Nn), dim3(128), 0, stream,
        node, hidden, graph, W_m1, b_m1, W_m2, b_m2, b_me, W_mg, b_mg,
        W_tn1, b_tn1, W_tn2, b_tn2, W_th1, b_th1, W_th2, b_th2,
        W_tg1, b_tg1, W_tg2, b_tg2, b_te1, b_te2,
        preA, preB, triA, triB, msgs_i, az);
    hipLaunchKernelGGL(k_prew, dim3(77), dim3(256), 0, stream,
        W_me, W_te1, W_te2, wt);
    hipLaunchKernelGGL(k_main, dim3(768), dim3(256), 0, stream,
        edge, adj, wt, preB, triA, triB, msgs_i, az, tri);
    hipLaunchKernelGGL(k_out, dim3(Bb * Nn), dim3(128), 0, stream,
        node, hidden, msgs_i, az, preA, W_o1, b_o1, W_o2, b_o2, W_o3, b_o3, ret);
}